// Round 11
// baseline (144.475 us; speedup 1.0000x reference)
//
#include <hip/hip_runtime.h>
#include <stdint.h>

#define B_DIM 32768
#define IN_DIM 512
#define OUT_DIM 512

typedef float f32x4 __attribute__((ext_vector_type(4)));
typedef long long2_t __attribute__((ext_vector_type(2)));

// xi = trunc(v*2^sf); keep top-4 significant bits of |xi|; sign restored.
// Masked fp32 value is an integer with <=4 significant bits, |v| <= ~370
// < 448 = e4m3 max -> OCP e4m3 represents it EXACTLY (absmax=0, R4/R6/R9).
__device__ __forceinline__ float trunc4(float x, float s) {
    uint32_t u = __float_as_uint(truncf(x * s));
    return __uint_as_float(u & 0xFFF00000u);   // sign+exp+3 mantissa bits
}

// w-only quant pre-pass (0.25 MB -> ~1.5 us). x is quantized inside the GEMM.
__global__ void quant_fp8(const float* __restrict__ in, uint32_t* __restrict__ out,
                          int n4, const int* __restrict__ sf) {
    int i = blockIdx.x * blockDim.x + threadIdx.x;
    if (i >= n4) return;
    float scale = (float)(1 << *sf);
    float4 v = ((const float4*)in)[i];
    int p = 0;
    p = __builtin_amdgcn_cvt_pk_fp8_f32(trunc4(v.x, scale), trunc4(v.y, scale), p, false);
    p = __builtin_amdgcn_cvt_pk_fp8_f32(trunc4(v.z, scale), trunc4(v.w, scale), p, true);
    out[i] = (uint32_t)p;   // byte j = element j (k-ascending)
}

// Fused quant(x) + fp8 GEMM. 128(M) x 256(N) tile, 512 thr / 8 waves (2Mx4N),
// per-wave 64x64 = acc[4][4] (verified R6/R9 math, b128-pair frag reads).
// Removes the quant_x pass: -34 MB tx round-trip, -1 dispatch; GEMM reads x
// f32 directly (x read ONCE from HBM: 2 sibling N-blocks share an XCD via
// the swizzle, second read L2-hit).
// Pipeline (counted vmcnt, W depth-2 / A depth-1-early):
//   iter k: issue A-loads(k+1)->regs [4, FIRST], glds W(k+2)->Ws[(k+2)%3] [2]
//           MFMA on As[k&1], Ws[k%3]            <- hides both latencies
//           s_waitcnt vmcnt(2)   <- A(k+1)+W(k+1) landed; W(k+2) STAYS IN
//                                   FLIGHT across the barrier (FIFO: A issued
//                                   before W(k+2), so vmcnt(2) = newest 2 left)
//           quant fr -> ds_write_b64 -> As[(k+1)&1]
//           s_waitcnt lgkmcnt(0); s_barrier      (ONE barrier per K-step)
// WAR: ds_write As[(k+1)&1] at end of iter k; that buffer was last read in
// iter k-1, drained by that iter's lgkmcnt(0)+barrier. W glds(k+2) writes
// Ws[(k-1)%3], last read iter k-1, same argument.
// LDS: 2x8KB A + 3x16KB W = 64 KB -> 2 blocks/CU (barrier bubbles covered).
// Layouts (verified): row r's 8B k-unit u at physical u^(r&6); A write side
// computes it directly, W via pre-swizzled glds source; read = b128 pair at
// chunk (q^((rl>>1)&3))*16, lo->even-unit MFMA, hi->odd (k-order exact:
// integer products < 2^24, fp32 add associative on them).
__global__ __launch_bounds__(512, 4)
void gemm_f8x(const float* __restrict__ X, const uint8_t* __restrict__ W,
              const float* __restrict__ bias, float* __restrict__ C,
              const int* __restrict__ wsf, const int* __restrict__ asf) {
    __shared__ uint8_t As[2][128 * 64];
    __shared__ uint8_t Ws[3][256 * 64];

    const int t    = threadIdx.x;
    const int w    = t >> 6;
    const int lane = t & 63;

    // XCD swizzle (bijective over 512): siblings (bn=0/1) of one M-band are
    // b and b+8 -> same XCD -> x rows L2-shared.
    const int b    = blockIdx.x;
    const int bm   = (b & 7) * 32 + (b >> 4);
    const int bn   = (b >> 3) & 1;
    const int row0 = bm * 128;
    const int col0 = bn * 256;
    const int wm   = (w & 1) * 64;
    const int wn   = (w >> 1) * 64;

    // W staging (glds): pass i covers rows i*128..+128; row m = i*128+(t>>2),
    // 16B chunk j = t&3 -> global byte offset ((2j)^(m&6))*8 in the row.
    const int mw   = t >> 2;
    const size_t offW = (size_t)(col0 + mw) * IN_DIM + ((2 * (t & 3)) ^ (mw & 6)) * 8;

    // A staging (reg-quant): group g covers row g*64+(t>>3), f32 cols
    // (t&7)*8..+8 (wave: 8 lanes x 32B = 256B contiguous per row).
    const float* xa = X + (size_t)(row0 + (t >> 3)) * IN_DIM + (t & 7) * 8;
    // LDS byte offset of that 8-fp8 unit: (row*8 + ((t&7)^(row&6)))*8, +g*4096.
    const int awoff = ((t >> 3) * 8 + ((t & 7) ^ ((t >> 3) & 6))) * 8;
    const float ascale = (float)(1 << *asf);

    f32x4 acc[4][4];
    #pragma unroll
    for (int mt = 0; mt < 4; ++mt)
        #pragma unroll
        for (int nt = 0; nt < 4; ++nt)
            acc[mt][nt] = 0.0f;

    float4 fr[2][2];   // [g][half], all indices compile-time

#define ISSUE_W(s, kt)                                                                        \
    {                                                                                         \
        _Pragma("unroll")                                                                     \
        for (int i = 0; i < 2; ++i) {                                                         \
            const uint8_t* gw = W + offW + (size_t)i * 128 * IN_DIM + (kt) * 64;              \
            uint8_t*       lw = &Ws[s][i * 8192 + w * 1024];                                  \
            __builtin_amdgcn_global_load_lds((const __attribute__((address_space(1))) void*)gw,\
                                             (__attribute__((address_space(3))) void*)lw, 16, 0, 0); \
        }                                                                                     \
    }

#define ISSUE_A(kt)                                                                           \
    {                                                                                         \
        _Pragma("unroll")                                                                     \
        for (int g = 0; g < 2; ++g)                                                           \
            _Pragma("unroll")                                                                 \
            for (int h = 0; h < 2; ++h)                                                       \
                fr[g][h] = *(const float4*)(xa + (size_t)g * 64 * IN_DIM + (kt) * 64 + h * 4);\
    }

#define QUANT_WRITE_A(s)                                                                      \
    {                                                                                         \
        _Pragma("unroll")                                                                     \
        for (int g = 0; g < 2; ++g) {                                                         \
            int p0 = 0, p1 = 0;                                                               \
            p0 = __builtin_amdgcn_cvt_pk_fp8_f32(trunc4(fr[g][0].x, ascale), trunc4(fr[g][0].y, ascale), p0, false); \
            p0 = __builtin_amdgcn_cvt_pk_fp8_f32(trunc4(fr[g][0].z, ascale), trunc4(fr[g][0].w, ascale), p0, true);  \
            p1 = __builtin_amdgcn_cvt_pk_fp8_f32(trunc4(fr[g][1].x, ascale), trunc4(fr[g][1].y, ascale), p1, false); \
            p1 = __builtin_amdgcn_cvt_pk_fp8_f32(trunc4(fr[g][1].z, ascale), trunc4(fr[g][1].w, ascale), p1, true);  \
            uint2 pq; pq.x = (uint32_t)p0; pq.y = (uint32_t)p1;                               \
            *(uint2*)(&As[s][awoff + g * 4096]) = pq;                                         \
        }                                                                                     \
    }

    // ---- prologue: W(0), A(0), W(1) issued; vmcnt(2) keeps W(1) in flight ----
    ISSUE_W(0, 0);
    ISSUE_A(0);
    ISSUE_W(1, 1);
    asm volatile("s_waitcnt vmcnt(2)" ::: "memory");
    __builtin_amdgcn_sched_barrier(0);
    QUANT_WRITE_A(0);
    asm volatile("s_waitcnt lgkmcnt(0)" ::: "memory");
    __builtin_amdgcn_sched_barrier(0);
    __builtin_amdgcn_s_barrier();
    __builtin_amdgcn_sched_barrier(0);

    #pragma unroll
    for (int k = 0; k < 8; ++k) {
        // ---- issue next work: A(k+1) FIRST (older in FIFO), then W(k+2) ----
        if (k < 7) ISSUE_A(k + 1);
        if (k < 6) ISSUE_W((k + 2) % 3, k + 2);
        __builtin_amdgcn_sched_barrier(0);   // pin: issues before compute

        // ---- MFMA phase on As[k&1], Ws[k%3]: b128-pair, even/odd MFMAs ----
        {
            const int q  = lane >> 4;
            const int rl = lane & 15;
            const int ch = (q ^ ((rl >> 1) & 3)) * 16;
            long2_t af[4], bfr[4];
            #pragma unroll
            for (int mt = 0; mt < 4; ++mt)
                af[mt] = *(const long2_t*)(&As[k & 1][0] + (wm + mt * 16 + rl) * 64 + ch);
            #pragma unroll
            for (int nt = 0; nt < 4; ++nt)
                bfr[nt] = *(const long2_t*)(&Ws[k % 3][0] + (wn + nt * 16 + rl) * 64 + ch);
            #pragma unroll
            for (int mt = 0; mt < 4; ++mt)
                #pragma unroll
                for (int nt = 0; nt < 4; ++nt) {
                    acc[mt][nt] = __builtin_amdgcn_mfma_f32_16x16x32_fp8_fp8(af[mt].x, bfr[nt].x, acc[mt][nt], 0, 0, 0);
                    acc[mt][nt] = __builtin_amdgcn_mfma_f32_16x16x32_fp8_fp8(af[mt].y, bfr[nt].y, acc[mt][nt], 0, 0, 0);
                }
        }

        // ---- counted wait; quant+write A(k+1); ONE barrier per K-step ----
        if (k < 7) {
            if (k < 6) {
                asm volatile("s_waitcnt vmcnt(2)" ::: "memory");   // W(k+2) in flight
            } else {
                asm volatile("s_waitcnt vmcnt(0)" ::: "memory");   // no W(8): drain
            }
            __builtin_amdgcn_sched_barrier(0);
            QUANT_WRITE_A((k + 1) & 1);
            asm volatile("s_waitcnt lgkmcnt(0)" ::: "memory");
            __builtin_amdgcn_sched_barrier(0);
            __builtin_amdgcn_s_barrier();
            __builtin_amdgcn_sched_barrier(0);
        }
    }

    // epilogue: C/D layout col=lane&15, row=(lane>>4)*4+reg (dtype-independent)
    const float oscale = ldexpf(1.0f, -(*wsf + *asf));
    const int cl = lane & 15;
    const int rg = (lane >> 4) * 4;
    #pragma unroll
    for (int nt = 0; nt < 4; ++nt) {
        const int col = col0 + wn + nt * 16 + cl;
        const float bv = bias[col];
        #pragma unroll
        for (int mt = 0; mt < 4; ++mt) {
            f32x4 a = acc[mt][nt];
            #pragma unroll
            for (int r = 0; r < 4; ++r) {
                const int row = row0 + wm + mt * 16 + rg + r;
                C[(size_t)row * OUT_DIM + col] = a[r] * oscale + bv;
            }
        }
    }
#undef ISSUE_W
#undef ISSUE_A
#undef QUANT_WRITE_A
}

extern "C" void kernel_launch(void* const* d_in, const int* in_sizes, int n_in,
                              void* d_out, int out_size, void* d_ws, size_t ws_size,
                              hipStream_t stream) {
    const float* x    = (const float*)d_in[0];
    const float* wgt  = (const float*)d_in[1];
    const float* bias = (const float*)d_in[2];
    const int*   wsf  = (const int*)d_in[3];
    const int*   asf  = (const int*)d_in[4];

    uint8_t* tw = (uint8_t*)d_ws;

    const int nw4 = OUT_DIM * IN_DIM / 4;
    quant_fp8<<<(nw4 + 255) / 256, 256, 0, stream>>>(wgt, (uint32_t*)tw, nw4, wsf);

    const int grid = (B_DIM / 128) * (OUT_DIM / 256); // 512
    gemm_f8x<<<grid, 512, 0, stream>>>(x, tw, bias, (float*)d_out, wsf, asf);
}

// Round 12
// 131.255 us; speedup vs baseline: 1.1007x; 1.1007x over previous
//
#include <hip/hip_runtime.h>
#include <stdint.h>

#define B_DIM 32768
#define IN_DIM 512
#define OUT_DIM 512

typedef float f32x4 __attribute__((ext_vector_type(4)));

// xi = trunc(v*2^sf); keep top-4 significant bits of |xi|; sign restored.
// fp32-bit path: truncf, then mask mantissa to 3 stored bits (+implicit = 4
// significant). The masked value is an integer with <=4 significant bits and
// |v| <= ~370 < 448 = e4m3 max, so OCP e4m3 represents it EXACTLY ->
// cvt_pk_fp8_f32 is lossless here (verified absmax=0 in R4/R6/R9/R10).
__device__ __forceinline__ float trunc4(float x, float s) {
    uint32_t u = __float_as_uint(truncf(x * s));
    return __uint_as_float(u & 0xFFF00000u);   // sign+exp+3 mantissa bits
}

// Merged quant, 8 elems/thread (G13) + grid-stride 2048 blocks (G11):
// 2x float4 load (32B/lane), 4x cvt_pk, one 8B uint2 store. vs R6's 4-wide
// scalar-store version: half the loads/stores/threads for the same bytes.
// Floor: 85.4 MB traffic ~ 13.6 us at 6.3 TB/s.
__global__ void quant_fp8_v8(const float* __restrict__ x, const float* __restrict__ w,
                             uint2* __restrict__ ox, uint2* __restrict__ ow,
                             int nx8, int nw8,
                             const int* __restrict__ asf, const int* __restrict__ wsf) {
    const float sx = (float)(1 << *asf);
    const float sw = (float)(1 << *wsf);
    const int stride = gridDim.x * blockDim.x;
    for (int i = blockIdx.x * blockDim.x + threadIdx.x; i < nx8 + nw8; i += stride) {
        const float4* in;
        uint2* out;
        float s;
        if (i < nx8) {
            in = (const float4*)x + 2 * (size_t)i;  out = ox + i;  s = sx;
        } else {
            int j = i - nx8;
            in = (const float4*)w + 2 * (size_t)j;  out = ow + j;  s = sw;
        }
        float4 v0 = in[0], v1 = in[1];
        int p0 = 0, p1 = 0;
        p0 = __builtin_amdgcn_cvt_pk_fp8_f32(trunc4(v0.x, s), trunc4(v0.y, s), p0, false);
        p0 = __builtin_amdgcn_cvt_pk_fp8_f32(trunc4(v0.z, s), trunc4(v0.w, s), p0, true);
        p1 = __builtin_amdgcn_cvt_pk_fp8_f32(trunc4(v1.x, s), trunc4(v1.y, s), p1, false);
        p1 = __builtin_amdgcn_cvt_pk_fp8_f32(trunc4(v1.z, s), trunc4(v1.w, s), p1, true);
        uint2 r;
        r.x = (uint32_t)p0;   // bytes 0-3 = elems 0-3 (k-ascending)
        r.y = (uint32_t)p1;   // bytes 4-7 = elems 4-7
        *out = r;
    }
}

// fp8 GEMM — byte-identical to the verified R6 best (131.9 us total):
// 2-phase double-buffered single-barrier pipeline (T3-minimum):
//   iter k: issue glds STAGE(k+1) -> buf[nxt]   (in flight across compute)
//           ds_read frags + 32 MFMA on buf[cur]
//           s_waitcnt vmcnt(0) lgkmcnt(0); s_barrier     (ONE per K-step)
// WAR-safe: iter k's glds writes buf[nxt]; buf[nxt] was last READ in iter k-1,
// strictly before the barrier that preceded these glds.
// Tile 128x128, BK=64, 4 waves 2x2, 4x4 MFMA 16x16x32_fp8_fp8, LDS swizzle
// unit p = u ^ (row&6) applied on the glds global source, ds_read_b64 frags.
__global__ __launch_bounds__(256, 4)
void gemm_f8(const uint8_t* __restrict__ A, const uint8_t* __restrict__ W,
             const float* __restrict__ bias, float* __restrict__ C,
             const int* __restrict__ wsf, const int* __restrict__ asf) {
    __shared__ uint8_t As[2][128 * 64];
    __shared__ uint8_t Bs[2][128 * 64];

    const int t    = threadIdx.x;
    const int w    = t >> 6;
    const int lane = t & 63;

    // XCD swizzle: 4 N-blocks of one M-band adjacent on one XCD (A L2 reuse).
    const int b    = blockIdx.x;
    const int xcd  = b & 7;
    const int slot = b >> 3;
    const int bm   = xcd * 32 + (slot >> 2);
    const int bn   = slot & 3;
    const int row0 = bm * 128;
    const int col0 = bn * 128;
    const int wm   = (w & 1) * 64;
    const int wn   = (w >> 1) * 64;

    // staging: pass i covers physical bytes [i*4096 + t*16, +16).
    // row m = i*64 + (t>>2); physical 16B unit j = t&3; global byte offset in
    // row = ((2j) ^ (m&6)) * 8  (16 contiguous bytes = 2 adjacent logical units).
    const int m_st = t >> 2;                       // 0..63 (+i*64; i*64 === 0 mod 8)
    const int goff = ((2 * (t & 3)) ^ (m_st & 6)) * 8;
    const size_t offA = (size_t)(row0 + m_st) * IN_DIM + goff;
    const size_t offB = (size_t)(col0 + m_st) * IN_DIM + goff;

    f32x4 acc[4][4];
    #pragma unroll
    for (int mt = 0; mt < 4; ++mt)
        #pragma unroll
        for (int nt = 0; nt < 4; ++nt)
            acc[mt][nt] = 0.0f;

    // ---- prologue: stage tile 0 into buffer 0 (one exposed latency) ----
    #pragma unroll
    for (int i = 0; i < 2; ++i) {
        const uint8_t* ga = A + offA + (size_t)i * 64 * IN_DIM;
        uint8_t*       la = &As[0][i * 4096 + w * 1024];   // + lane*16B by HW
        __builtin_amdgcn_global_load_lds((const __attribute__((address_space(1))) void*)ga,
                                         (__attribute__((address_space(3))) void*)la, 16, 0, 0);
        const uint8_t* gb = W + offB + (size_t)i * 64 * IN_DIM;
        uint8_t*       lb = &Bs[0][i * 4096 + w * 1024];
        __builtin_amdgcn_global_load_lds((const __attribute__((address_space(1))) void*)gb,
                                         (__attribute__((address_space(3))) void*)lb, 16, 0, 0);
    }
    asm volatile("s_waitcnt vmcnt(0) lgkmcnt(0)" ::: "memory");
    __builtin_amdgcn_sched_barrier(0);
    __builtin_amdgcn_s_barrier();
    __builtin_amdgcn_sched_barrier(0);

    #pragma unroll
    for (int k = 0; k < 8; ++k) {
        const int cur = k & 1;
        const int nxt = cur ^ 1;

        // ---- issue STAGE(k+1) early: in flight across the MFMA phase ----
        if (k < 7) {
            #pragma unroll
            for (int i = 0; i < 2; ++i) {
                const uint8_t* ga = A + offA + (size_t)i * 64 * IN_DIM + (k + 1) * 64;
                uint8_t*       la = &As[nxt][i * 4096 + w * 1024];
                __builtin_amdgcn_global_load_lds((const __attribute__((address_space(1))) void*)ga,
                                                 (__attribute__((address_space(3))) void*)la, 16, 0, 0);
                const uint8_t* gb = W + offB + (size_t)i * 64 * IN_DIM + (k + 1) * 64;
                uint8_t*       lb = &Bs[nxt][i * 4096 + w * 1024];
                __builtin_amdgcn_global_load_lds((const __attribute__((address_space(1))) void*)gb,
                                                 (__attribute__((address_space(3))) void*)lb, 16, 0, 0);
            }
        }
        __builtin_amdgcn_sched_barrier(0);   // pin: glds issued before compute

        // ---- MFMA phase on buffers[cur] ----
        {
            const int q  = lane >> 4;
            const int rl = lane & 15;
            const int sx = rl & 6;              // = row&6 (wm, mt*16 are mult of 8)
            #pragma unroll
            for (int ks = 0; ks < 2; ++ks) {
                const int c  = ks * 4 + q;      // logical 8B k-unit
                const int cb = (c ^ sx) * 8;    // swizzled byte offset in row
                long af[4], bfr[4];
                #pragma unroll
                for (int mt = 0; mt < 4; ++mt)
                    af[mt] = *(const long*)(&As[cur][0] + (wm + mt * 16 + rl) * 64 + cb);
                #pragma unroll
                for (int nt = 0; nt < 4; ++nt)
                    bfr[nt] = *(const long*)(&Bs[cur][0] + (wn + nt * 16 + rl) * 64 + cb);
                #pragma unroll
                for (int mt = 0; mt < 4; ++mt)
                    #pragma unroll
                    for (int nt = 0; nt < 4; ++nt)
                        acc[mt][nt] = __builtin_amdgcn_mfma_f32_16x16x32_fp8_fp8(af[mt], bfr[nt], acc[mt][nt], 0, 0, 0);
            }
        }

        // ---- ONE drain + barrier per K-step ----
        if (k < 7) {
            asm volatile("s_waitcnt vmcnt(0) lgkmcnt(0)" ::: "memory");
            __builtin_amdgcn_sched_barrier(0);
            __builtin_amdgcn_s_barrier();
            __builtin_amdgcn_sched_barrier(0);
        }
    }

    // epilogue: C/D layout col=lane&15, row=(lane>>4)*4+reg (dtype-independent)
    const float oscale = ldexpf(1.0f, -(*wsf + *asf));
    const int cl = lane & 15;
    const int rg = (lane >> 4) * 4;
    #pragma unroll
    for (int nt = 0; nt < 4; ++nt) {
        const int col = col0 + wn + nt * 16 + cl;
        const float bv = bias[col];
        #pragma unroll
        for (int mt = 0; mt < 4; ++mt) {
            f32x4 a = acc[mt][nt];
            #pragma unroll
            for (int r = 0; r < 4; ++r) {
                const int row = row0 + wm + mt * 16 + rg + r;
                C[(size_t)row * OUT_DIM + col] = a[r] * oscale + bv;
            }
        }
    }
}

extern "C" void kernel_launch(void* const* d_in, const int* in_sizes, int n_in,
                              void* d_out, int out_size, void* d_ws, size_t ws_size,
                              hipStream_t stream) {
    const float* x    = (const float*)d_in[0];
    const float* wgt  = (const float*)d_in[1];
    const float* bias = (const float*)d_in[2];
    const int*   wsf  = (const int*)d_in[3];
    const int*   asf  = (const int*)d_in[4];

    uint8_t* tx = (uint8_t*)d_ws;
    uint8_t* tw = (uint8_t*)d_ws + (size_t)B_DIM * IN_DIM;

    const int nx8 = B_DIM * IN_DIM / 8;
    const int nw8 = OUT_DIM * IN_DIM / 8;
    quant_fp8_v8<<<2048, 256, 0, stream>>>(
        x, wgt, (uint2*)tx, (uint2*)tw, nx8, nw8, asf, wsf);

    const int grid = (B_DIM / 128) * (OUT_DIM / 128); // 1024
    gemm_f8<<<grid, 256, 0, stream>>>(tx, tw, bias, (float*)d_out, wsf, asf);
}